// Round 1
// baseline (205.744 us; speedup 1.0000x reference)
//
#include <hip/hip_runtime.h>
#include <hip/hip_bf16.h>

// ---------------------------------------------------------------------------
// UncertaintyAwareQNetwork: E=5 ensemble x NS=10 MC samples, B=4096 rows.
// Per-row MLP 256 -> 256 -> 256 -> 18 with Bayesian (reparameterized) weights,
// then ensemble mean/var, uncertainty head, risk head, KL term.
//
// Pipeline:
//   scvt:   state f32 -> bf16 row-major [4096][256]
//   wgen:   realized weights (mu + softplus(rho)*eps) -> bf16, MFMA-frag-major
//   bgen:   realized biases -> f32
//   kl:     two-stage deterministic reduction -> d_out[446464]
//   mlp:    fused 3-layer MFMA kernel per (es, 64-row tile) -> y2[es][18][4096]
//   stats:  mean/var over ensemble -> q_mean, epistemic
//   heads:  uncertainty + risk heads -> aleatoric/total/lcb/ucb/risk
// ---------------------------------------------------------------------------

typedef __bf16 bf16x8 __attribute__((ext_vector_type(8)));
typedef float f32x4 __attribute__((ext_vector_type(4)));
typedef unsigned short u16x4 __attribute__((ext_vector_type(4)));
typedef unsigned short u16x8 __attribute__((ext_vector_type(8)));

#define E_DIM 5
#define NS 10
#define ES 50
#define B_DIM 4096
#define A_DIM 18

__device__ __forceinline__ unsigned short f2bf(float f) {
  unsigned int u = __builtin_bit_cast(unsigned int, f);
  u += 0x7fffu + ((u >> 16) & 1u);
  return (unsigned short)(u >> 16);
}

__device__ __forceinline__ float softplus_f(float x) {
  return (x > 20.f) ? x : log1pf(expf(x));
}

__device__ __forceinline__ f32x4 mfma16(bf16x8 a, bf16x8 b, f32x4 c) {
  return __builtin_amdgcn_mfma_f32_16x16x32_bf16(a, b, c, 0, 0, 0);
}

// --------------------------- state f32 -> bf16 ------------------------------
__global__ __launch_bounds__(256) void scvt_kernel(const float* __restrict__ s,
                                                   unsigned short* __restrict__ d) {
  int gid = blockIdx.x * 256 + threadIdx.x;  // 131072 groups of 8
  const f32x4* p = (const f32x4*)(s + (size_t)gid * 8);
  f32x4 x0 = p[0], x1 = p[1];
  u16x8 v = {f2bf(x0.x), f2bf(x0.y), f2bf(x0.z), f2bf(x0.w),
             f2bf(x1.x), f2bf(x1.y), f2bf(x1.z), f2bf(x1.w)};
  *(u16x8*)(d + (size_t)gid * 8) = v;
}

// ------------------- realized weights, MFMA-frag-major ----------------------
// Layout: frag id = (es*(OPAD/16) + osub)*8 + kt ; within frag: lane*16B.
// Lane l of frag holds W[o = osub*16 + l%16][i = kt*32 + (l/16)*8 + 0..7].
template <int O, int OPAD>
__global__ __launch_bounds__(256) void wgen_kernel(const float* __restrict__ wmu,
                                                   const float* __restrict__ wrho,
                                                   const float* __restrict__ weps,
                                                   char* __restrict__ wf) {
  int gid = blockIdx.x * 256 + threadIdx.x;  // ES*OPAD*32 groups (8 i's each)
  int es = gid / (OPAD * 32);
  int rem = gid - es * (OPAD * 32);
  int o = rem >> 5;
  int i8 = (rem & 31) * 8;
  int e = es / 10, s = es - e * 10;
  float v[8];
  if (O == OPAD || o < O) {
    const float* mu = wmu + ((size_t)(e * O + o)) * 256 + i8;
    const float* rho = wrho + ((size_t)(e * O + o)) * 256 + i8;
    const float* eps = weps + ((size_t)((e * 10 + s) * O + o)) * 256 + i8;
#pragma unroll
    for (int j = 0; j < 8; ++j) v[j] = mu[j] + softplus_f(rho[j]) * eps[j];
  } else {
#pragma unroll
    for (int j = 0; j < 8; ++j) v[j] = 0.f;
  }
  u16x8 pk = {f2bf(v[0]), f2bf(v[1]), f2bf(v[2]), f2bf(v[3]),
              f2bf(v[4]), f2bf(v[5]), f2bf(v[6]), f2bf(v[7])};
  int osub = o >> 4, om = o & 15, kt = i8 >> 5, jj = (i8 >> 3) & 3;
  int lane = jj * 16 + om;
  *(u16x8*)(wf + (size_t)(((es * (OPAD / 16) + osub) * 8 + kt) * 64 + lane) * 16) = pk;
}

// ----------------------------- realized biases ------------------------------
__global__ __launch_bounds__(256) void bgen_kernel(
    const float* bmu0, const float* brho0, const float* beps0,
    const float* bmu1, const float* brho1, const float* beps1,
    const float* bmu2, const float* brho2, const float* beps2,
    float* bias0, float* bias1, float* bias2) {
  int gid = blockIdx.x * 256 + threadIdx.x;
  if (gid < 12800) {
    int es = gid >> 8, o = gid & 255, e = es / 10, s = es - e * 10;
    bias0[gid] = bmu0[e * 256 + o] + softplus_f(brho0[e * 256 + o]) * beps0[(e * 10 + s) * 256 + o];
  } else if (gid < 25600) {
    int id = gid - 12800;
    int es = id >> 8, o = id & 255, e = es / 10, s = es - e * 10;
    bias1[id] = bmu1[e * 256 + o] + softplus_f(brho1[e * 256 + o]) * beps1[(e * 10 + s) * 256 + o];
  } else if (gid < 27200) {
    int id = gid - 25600;
    int es = id >> 5, o = id & 31, e = es / 10, s = es - e * 10;
    bias2[id] = (o < 18)
        ? bmu2[e * 18 + o] + softplus_f(brho2[e * 18 + o]) * beps2[(e * 10 + s) * 18 + o]
        : 0.f;
  }
}

// --------------------------------- KL ---------------------------------------
__global__ __launch_bounds__(256) void kl_kernel(
    const float* wmu0, const float* wrho0, const float* wmu1, const float* wrho1,
    const float* wmu2, const float* wrho2, const float* bmu0, const float* brho0,
    const float* bmu1, const float* brho1, const float* bmu2, const float* brho2,
    float* __restrict__ partials) {
  float acc = 0.f;
  for (int i = blockIdx.x * 256 + threadIdx.x; i < 681050; i += 512 * 256) {
    const float *mu, *rho;
    int j = i;
    if (j < 327680) { mu = wmu0; rho = wrho0; }
    else if ((j -= 327680) < 327680) { mu = wmu1; rho = wrho1; }
    else if ((j -= 327680) < 23040) { mu = wmu2; rho = wrho2; }
    else if ((j -= 23040) < 1280) { mu = bmu0; rho = brho0; }
    else if ((j -= 1280) < 1280) { mu = bmu1; rho = brho1; }
    else { j -= 1280; mu = bmu2; rho = brho2; }
    float m = mu[j];
    float sg = softplus_f(rho[j]);
    acc += -logf(sg) + (sg * sg + m * m) * 0.5f - 0.5f;
  }
#pragma unroll
  for (int m = 32; m >= 1; m >>= 1) acc += __shfl_xor(acc, m);
  __shared__ float wsum[4];
  if ((threadIdx.x & 63) == 0) wsum[threadIdx.x >> 6] = acc;
  __syncthreads();
  if (threadIdx.x == 0) partials[blockIdx.x] = wsum[0] + wsum[1] + wsum[2] + wsum[3];
}

__global__ __launch_bounds__(256) void kl_final(const float* __restrict__ partials,
                                                float* __restrict__ out) {
  float acc = 0.f;
  for (int i = threadIdx.x; i < 512; i += 256) acc += partials[i];
#pragma unroll
  for (int m = 32; m >= 1; m >>= 1) acc += __shfl_xor(acc, m);
  __shared__ float wsum[4];
  if ((threadIdx.x & 63) == 0) wsum[threadIdx.x >> 6] = acc;
  __syncthreads();
  if (threadIdx.x == 0) out[446464] = (wsum[0] + wsum[1] + wsum[2] + wsum[3]) * 0.2f;
}

// ------------------------------ fused MLP ------------------------------------
// Transposed formulation: D[o][b] = sum_i W[o][i] * x[b][i].
// A-frag (weights) from global frag-major; B-frag (activations) in LDS frag-major.
// Epilogue packs bias+relu+bf16 directly into next layer's B-frag layout.
template <int RELU>
__device__ __forceinline__ void mlp_layer(const char* __restrict__ wf,
                                          const float* __restrict__ bias,
                                          int obase,
                                          const char* __restrict__ bufB,
                                          char* __restrict__ bufX, int lane) {
  f32x4 acc[4][4];
  f32x4 zero = {0.f, 0.f, 0.f, 0.f};
#pragma unroll
  for (int i = 0; i < 4; ++i)
#pragma unroll
    for (int j = 0; j < 4; ++j) acc[i][j] = zero;

#pragma unroll
  for (int kt = 0; kt < 8; ++kt) {
    bf16x8 bfr[4], afr[4];
#pragma unroll
    for (int bt = 0; bt < 4; ++bt)
      bfr[bt] = *(const bf16x8*)(bufB + (bt * 8 + kt) * 1024 + lane * 16);
#pragma unroll
    for (int ot = 0; ot < 4; ++ot)
      afr[ot] = *(const bf16x8*)(wf + (ot * 8 + kt) * 1024 + lane * 16);
#pragma unroll
    for (int ot = 0; ot < 4; ++ot)
#pragma unroll
      for (int bt = 0; bt < 4; ++bt) acc[ot][bt] = mfma16(afr[ot], bfr[bt], acc[ot][bt]);
  }

  int g = lane >> 4, lm = lane & 15;
#pragma unroll
  for (int ot = 0; ot < 4; ++ot) {
    f32x4 bv = *(const f32x4*)(bias + ot * 16 + 4 * g);
    int i0 = obase + ot * 16 + 4 * g;          // output index of reg r=0
    int ktp = i0 >> 5;
    int lanep = ((i0 & 31) >> 3) * 16 + lm;
    int byo = (i0 & 7) * 2;                    // 0 or 8
#pragma unroll
    for (int bt = 0; bt < 4; ++bt) {
      float v0 = acc[ot][bt].x + bv.x;
      float v1 = acc[ot][bt].y + bv.y;
      float v2 = acc[ot][bt].z + bv.z;
      float v3 = acc[ot][bt].w + bv.w;
      if (RELU) {
        v0 = fmaxf(v0, 0.f); v1 = fmaxf(v1, 0.f);
        v2 = fmaxf(v2, 0.f); v3 = fmaxf(v3, 0.f);
      }
      u16x4 pk = {f2bf(v0), f2bf(v1), f2bf(v2), f2bf(v3)};
      *(u16x4*)(bufX + (bt * 8 + ktp) * 1024 + lanep * 16 + byo) = pk;
    }
  }
}

__global__ __launch_bounds__(256, 2) void mlp_fused(
    const unsigned short* __restrict__ stateb, const char* __restrict__ W0f,
    const char* __restrict__ W1f, const char* __restrict__ W2f,
    const float* __restrict__ bias0, const float* __restrict__ bias1,
    const float* __restrict__ bias2, float* __restrict__ y2) {
  __shared__ char lds[65536];
  char* bufA = lds;            // state frags, later x2 frags
  char* bufX = lds + 32768;    // x1 frags
  int tid = threadIdx.x, w = tid >> 6, lane = tid & 63;
  int es = blockIdx.y, b0 = blockIdx.x * 64;

  // stage state tile [64 rows][256] as 32 B-frags (1 KB each), reg-staged
#pragma unroll
  for (int it = 0; it < 8; ++it) {
    int F = it * 4 + w, bt = F >> 3, kt = F & 7;
    const unsigned short* src =
        stateb + (size_t)(b0 + bt * 16 + (lane & 15)) * 256 + kt * 32 + (lane >> 4) * 8;
    u16x8 v = *(const u16x8*)src;
    *(u16x8*)(bufA + F * 1024 + lane * 16) = v;
  }
  __syncthreads();

  mlp_layer<1>(W0f + (size_t)(es * 16 + w * 4) * 8 * 1024, bias0 + es * 256 + w * 64,
               w * 64, bufA, bufX, lane);
  __syncthreads();
  mlp_layer<1>(W1f + (size_t)(es * 16 + w * 4) * 8 * 1024, bias1 + es * 256 + w * 64,
               w * 64, bufX, bufA, lane);
  __syncthreads();

  // layer 2: O padded to 32; wave w handles b-subtile bt=w, both o-subtiles
  f32x4 zero = {0.f, 0.f, 0.f, 0.f};
  f32x4 acc2[2] = {zero, zero};
  const char* w2 = W2f + (size_t)es * 16 * 1024;
#pragma unroll
  for (int kt = 0; kt < 8; ++kt) {
    bf16x8 b = *(const bf16x8*)(bufA + (w * 8 + kt) * 1024 + lane * 16);
    bf16x8 a0 = *(const bf16x8*)(w2 + kt * 1024 + lane * 16);
    bf16x8 a1 = *(const bf16x8*)(w2 + (8 + kt) * 1024 + lane * 16);
    acc2[0] = mfma16(a0, b, acc2[0]);
    acc2[1] = mfma16(a1, b, acc2[1]);
  }
  int g = lane >> 4, lm = lane & 15;
  int b_idx = b0 + w * 16 + lm;
#pragma unroll
  for (int ot = 0; ot < 2; ++ot) {
    f32x4 bv = *(const f32x4*)(bias2 + es * 32 + ot * 16 + 4 * g);
#pragma unroll
    for (int r = 0; r < 4; ++r) {
      int o = ot * 16 + 4 * g + r;
      float v = (r == 0 ? acc2[ot].x : r == 1 ? acc2[ot].y : r == 2 ? acc2[ot].z : acc2[ot].w);
      if (o < 18) y2[(size_t)(es * 18 + o) * 4096 + b_idx] = v + (r == 0 ? bv.x : r == 1 ? bv.y : r == 2 ? bv.z : bv.w);
    }
  }
}

// ------------------------- ensemble mean / variance --------------------------
__global__ __launch_bounds__(256) void stats_kernel(const float* __restrict__ y2,
                                                    float* __restrict__ out) {
  int idx = blockIdx.x * 256 + threadIdx.x;  // a*4096 + b
  if (idx >= 18 * 4096) return;
  int a = idx >> 12, b = idx & 4095;
  float qs = 0.f, qq = 0.f;
#pragma unroll
  for (int e = 0; e < 5; ++e) {
    float v = 0.f;
#pragma unroll
    for (int s = 0; s < 10; ++s) v += y2[(size_t)((e * 10 + s) * 18 + a) * 4096 + b];
    v *= 0.1f;
    qs += v;
    qq += v * v;
  }
  float mean = qs * 0.2f;
  float var = fmaxf((qq - 5.f * mean * mean) * 0.25f, 0.f);
  out[b * 18 + a] = mean;
  out[73728 + b * 18 + a] = var;
}

// ------------------------------- heads ---------------------------------------
__global__ __launch_bounds__(256) void heads_kernel(
    const float* __restrict__ uh_w1, const float* __restrict__ uh_b1,
    const float* __restrict__ uh_w2, const float* __restrict__ uh_b2,
    const float* __restrict__ rh_w1, const float* __restrict__ rh_b1,
    const float* __restrict__ rh_w2, const float* __restrict__ rh_b2,
    float* __restrict__ out) {
  __shared__ float rin[54];
  __shared__ float h[256];
  int b = blockIdx.x, t = threadIdx.x;
  if (t < 36) rin[t] = (t < 18) ? out[b * 18 + t] : out[73728 + b * 18 + (t - 18)];
  __syncthreads();

  // uncertainty hidden layer: h[t] = relu(u_in . uh_w1[t])
  {
    float acc = uh_b1[t];
#pragma unroll
    for (int j = 0; j < 36; ++j) acc += rin[j] * uh_w1[t * 36 + j];
    h[t] = fmaxf(acc, 0.f);
  }
  __syncthreads();

  int w = t >> 6, lane = t & 63;
  for (int idx = 0; idx < 5; ++idx) {
    int a = idx * 4 + w;
    if (a < 18) {
      float p = 0.f;
#pragma unroll
      for (int j = 0; j < 4; ++j) p += h[lane + 64 * j] * uh_w2[a * 256 + lane + 64 * j];
#pragma unroll
      for (int m = 32; m >= 1; m >>= 1) p += __shfl_xor(p, m);
      if (lane == 0) {
        float alea = softplus_f(p + uh_b2[a]);
        float qm = rin[a], epi = rin[18 + a];
        float tu = epi + alea;
        float s2 = 2.f * sqrtf(tu);
        out[2 * 73728 + b * 18 + a] = alea;
        out[3 * 73728 + b * 18 + a] = tu;
        out[4 * 73728 + b * 18 + a] = qm - s2;
        out[5 * 73728 + b * 18 + a] = qm + s2;
        rin[36 + a] = alea;
      }
    }
  }
  __syncthreads();

  // risk hidden layer
  {
    float acc = rh_b1[t];
#pragma unroll
    for (int j = 0; j < 54; ++j) acc += rin[j] * rh_w1[t * 54 + j];
    h[t] = fmaxf(acc, 0.f);
  }
  __syncthreads();
  if (w == 0) {
    float p = 0.f;
#pragma unroll
    for (int j = 0; j < 4; ++j) p += h[lane + 64 * j] * rh_w2[lane + 64 * j];
#pragma unroll
    for (int m = 32; m >= 1; m >>= 1) p += __shfl_xor(p, m);
    if (lane == 0) out[6 * 73728 + b] = p + rh_b2[0];
  }
}

// ------------------------------ launch ---------------------------------------
extern "C" void kernel_launch(void* const* d_in, const int* in_sizes, int n_in,
                              void* d_out, int out_size, void* d_ws, size_t ws_size,
                              hipStream_t stream) {
  const float* state = (const float*)d_in[0];
  const float* w_mu0 = (const float*)d_in[2];
  const float* w_rho0 = (const float*)d_in[3];
  const float* b_mu0 = (const float*)d_in[4];
  const float* b_rho0 = (const float*)d_in[5];
  const float* w_eps0 = (const float*)d_in[6];
  const float* b_eps0 = (const float*)d_in[7];
  const float* w_mu1 = (const float*)d_in[8];
  const float* w_rho1 = (const float*)d_in[9];
  const float* b_mu1 = (const float*)d_in[10];
  const float* b_rho1 = (const float*)d_in[11];
  const float* w_eps1 = (const float*)d_in[12];
  const float* b_eps1 = (const float*)d_in[13];
  const float* w_mu2 = (const float*)d_in[14];
  const float* w_rho2 = (const float*)d_in[15];
  const float* b_mu2 = (const float*)d_in[16];
  const float* b_rho2 = (const float*)d_in[17];
  const float* w_eps2 = (const float*)d_in[18];
  const float* b_eps2 = (const float*)d_in[19];
  const float* uh_w1 = (const float*)d_in[20];
  const float* uh_b1 = (const float*)d_in[21];
  const float* uh_w2 = (const float*)d_in[22];
  const float* uh_b2 = (const float*)d_in[23];
  const float* rh_w1 = (const float*)d_in[24];
  const float* rh_b1 = (const float*)d_in[25];
  const float* rh_w2 = (const float*)d_in[26];
  const float* rh_b2 = (const float*)d_in[27];
  float* out = (float*)d_out;

  char* ws = (char*)d_ws;
  unsigned short* stateb = (unsigned short*)ws;          // 2 MB
  char* W0f = ws + 2097152;                              // 6.55 MB
  char* W1f = W0f + 6553600;
  char* W2f = W1f + 6553600;                             // 0.82 MB
  float* bias0 = (float*)(W2f + 819200);                 // 12800 f
  float* bias1 = bias0 + 12800;
  float* bias2 = bias1 + 12800;                          // 1600 f
  float* y2 = bias2 + 1600;                              // 50*18*4096 f
  float* klpart = y2 + (size_t)50 * 18 * 4096;           // 512 f

  scvt_kernel<<<512, 256, 0, stream>>>(state, stateb);
  wgen_kernel<256, 256><<<1600, 256, 0, stream>>>(w_mu0, w_rho0, w_eps0, W0f);
  wgen_kernel<256, 256><<<1600, 256, 0, stream>>>(w_mu1, w_rho1, w_eps1, W1f);
  wgen_kernel<18, 32><<<200, 256, 0, stream>>>(w_mu2, w_rho2, w_eps2, W2f);
  bgen_kernel<<<107, 256, 0, stream>>>(b_mu0, b_rho0, b_eps0, b_mu1, b_rho1, b_eps1,
                                       b_mu2, b_rho2, b_eps2, bias0, bias1, bias2);
  kl_kernel<<<512, 256, 0, stream>>>(w_mu0, w_rho0, w_mu1, w_rho1, w_mu2, w_rho2,
                                     b_mu0, b_rho0, b_mu1, b_rho1, b_mu2, b_rho2, klpart);
  kl_final<<<1, 256, 0, stream>>>(klpart, out);
  mlp_fused<<<dim3(64, 50), 256, 0, stream>>>(stateb, W0f, W1f, W2f, bias0, bias1,
                                              bias2, y2);
  stats_kernel<<<288, 256, 0, stream>>>(y2, out);
  heads_kernel<<<4096, 256, 0, stream>>>(uh_w1, uh_b1, uh_w2, uh_b2, rh_w1, rh_b1,
                                         rh_w2, rh_b2, out);
}

// Round 2
// 170.336 us; speedup vs baseline: 1.2079x; 1.2079x over previous
//
#include <hip/hip_runtime.h>
#include <hip/hip_bf16.h>

// ---------------------------------------------------------------------------
// UncertaintyAwareQNetwork: E=5 ensemble x NS=10 MC samples, B=4096 rows.
// Pipeline (4 dispatches):
//   prep:   state->bf16, realized weights (MFMA-frag-major), biases, KL partials
//   mlp:    fused 3-layer MFMA kernel, 512 thr/block, per (es, 64-row tile)
//   stats:  mean/var over ensemble + KL final reduce
//   heads:  uncertainty + risk heads
// ---------------------------------------------------------------------------

typedef __bf16 bf16x8 __attribute__((ext_vector_type(8)));
typedef float f32x4 __attribute__((ext_vector_type(4)));
typedef unsigned short u16x4 __attribute__((ext_vector_type(4)));
typedef unsigned short u16x8 __attribute__((ext_vector_type(8)));

__device__ __forceinline__ unsigned short f2bf(float f) {
  unsigned int u = __builtin_bit_cast(unsigned int, f);
  u += 0x7fffu + ((u >> 16) & 1u);
  return (unsigned short)(u >> 16);
}

__device__ __forceinline__ float softplus_f(float x) {
  return (x > 20.f) ? x : log1pf(expf(x));
}

__device__ __forceinline__ f32x4 mfma16(bf16x8 a, bf16x8 b, f32x4 c) {
  return __builtin_amdgcn_mfma_f32_16x16x32_bf16(a, b, c, 0, 0, 0);
}

// ------------------- prep bodies (fused into one kernel) --------------------

__device__ __forceinline__ void scvt_body(int gid, const float* __restrict__ s,
                                          unsigned short* __restrict__ d) {
  const f32x4* p = (const f32x4*)(s + (size_t)gid * 8);
  f32x4 x0 = p[0], x1 = p[1];
  u16x8 v = {f2bf(x0.x), f2bf(x0.y), f2bf(x0.z), f2bf(x0.w),
             f2bf(x1.x), f2bf(x1.y), f2bf(x1.z), f2bf(x1.w)};
  *(u16x8*)(d + (size_t)gid * 8) = v;
}

// frag id = (es*(OPAD/16) + osub)*8 + kt ; lane l holds
// W[o = osub*16 + l%16][i = kt*32 + (l/16)*8 + 0..7]
template <int O, int OPAD>
__device__ __forceinline__ void wgen_body(int gid, const float* __restrict__ wmu,
                                          const float* __restrict__ wrho,
                                          const float* __restrict__ weps,
                                          char* __restrict__ wf) {
  int es = gid / (OPAD * 32);
  int rem = gid - es * (OPAD * 32);
  int o = rem >> 5;
  int i8 = (rem & 31) * 8;
  int e = es / 10, s = es - e * 10;
  float v[8];
  if (O == OPAD || o < O) {
    const float* mu = wmu + ((size_t)(e * O + o)) * 256 + i8;
    const float* rho = wrho + ((size_t)(e * O + o)) * 256 + i8;
    const float* eps = weps + ((size_t)((e * 10 + s) * O + o)) * 256 + i8;
#pragma unroll
    for (int j = 0; j < 8; ++j) v[j] = mu[j] + softplus_f(rho[j]) * eps[j];
  } else {
#pragma unroll
    for (int j = 0; j < 8; ++j) v[j] = 0.f;
  }
  u16x8 pk = {f2bf(v[0]), f2bf(v[1]), f2bf(v[2]), f2bf(v[3]),
              f2bf(v[4]), f2bf(v[5]), f2bf(v[6]), f2bf(v[7])};
  int osub = o >> 4, om = o & 15, kt = i8 >> 5, jj = (i8 >> 3) & 3;
  int lane = jj * 16 + om;
  *(u16x8*)(wf + (size_t)(((es * (OPAD / 16) + osub) * 8 + kt) * 64 + lane) * 16) = pk;
}

__global__ __launch_bounds__(256) void prep_kernel(
    const float* __restrict__ state, unsigned short* __restrict__ stateb,
    const float* __restrict__ wmu0, const float* __restrict__ wrho0,
    const float* __restrict__ weps0, char* __restrict__ W0f,
    const float* __restrict__ wmu1, const float* __restrict__ wrho1,
    const float* __restrict__ weps1, char* __restrict__ W1f,
    const float* __restrict__ wmu2, const float* __restrict__ wrho2,
    const float* __restrict__ weps2, char* __restrict__ W2f,
    const float* __restrict__ bmu0, const float* __restrict__ brho0,
    const float* __restrict__ beps0, const float* __restrict__ bmu1,
    const float* __restrict__ brho1, const float* __restrict__ beps1,
    const float* __restrict__ bmu2, const float* __restrict__ brho2,
    const float* __restrict__ beps2, float* __restrict__ bias0,
    float* __restrict__ bias1, float* __restrict__ bias2,
    float* __restrict__ partials) {
  int bid = blockIdx.x, t = threadIdx.x;
  if (bid < 512) {
    scvt_body(bid * 256 + t, state, stateb);
  } else if (bid < 2112) {
    wgen_body<256, 256>((bid - 512) * 256 + t, wmu0, wrho0, weps0, W0f);
  } else if (bid < 3712) {
    wgen_body<256, 256>((bid - 2112) * 256 + t, wmu1, wrho1, weps1, W1f);
  } else if (bid < 3912) {
    wgen_body<18, 32>((bid - 3712) * 256 + t, wmu2, wrho2, weps2, W2f);
  } else if (bid < 4019) {
    int gid = (bid - 3912) * 256 + t;
    if (gid < 12800) {
      int es = gid >> 8, o = gid & 255, e = es / 10, s = es - e * 10;
      bias0[gid] = bmu0[e * 256 + o] + softplus_f(brho0[e * 256 + o]) * beps0[(e * 10 + s) * 256 + o];
    } else if (gid < 25600) {
      int id = gid - 12800;
      int es = id >> 8, o = id & 255, e = es / 10, s = es - e * 10;
      bias1[id] = bmu1[e * 256 + o] + softplus_f(brho1[e * 256 + o]) * beps1[(e * 10 + s) * 256 + o];
    } else if (gid < 27200) {
      int id = gid - 25600;
      int es = id >> 5, o = id & 31, e = es / 10, s = es - e * 10;
      bias2[id] = (o < 18)
          ? bmu2[e * 18 + o] + softplus_f(brho2[e * 18 + o]) * beps2[(e * 10 + s) * 18 + o]
          : 0.f;
    }
  } else {
    int lb = bid - 4019;  // 0..511
    float acc = 0.f;
    for (int i = lb * 256 + t; i < 681050; i += 512 * 256) {
      const float *mu, *rho;
      int j = i;
      if (j < 327680) { mu = wmu0; rho = wrho0; }
      else if ((j -= 327680) < 327680) { mu = wmu1; rho = wrho1; }
      else if ((j -= 327680) < 23040) { mu = wmu2; rho = wrho2; }
      else if ((j -= 23040) < 1280) { mu = bmu0; rho = brho0; }
      else if ((j -= 1280) < 1280) { mu = bmu1; rho = brho1; }
      else { j -= 1280; mu = bmu2; rho = brho2; }
      float m = mu[j];
      float sg = softplus_f(rho[j]);
      acc += -logf(sg) + (sg * sg + m * m) * 0.5f - 0.5f;
    }
#pragma unroll
    for (int m = 32; m >= 1; m >>= 1) acc += __shfl_xor(acc, m);
    __shared__ float wsum[4];
    if ((t & 63) == 0) wsum[t >> 6] = acc;
    __syncthreads();
    if (t == 0) partials[lb] = wsum[0] + wsum[1] + wsum[2] + wsum[3];
  }
}

// ------------------------------ fused MLP ------------------------------------
// Transposed formulation: D[o][b] = sum_i W[o][i] * x[b][i].
// 8 waves/block; wave w owns o-subtiles {2w, 2w+1} (obase = 32w).
template <int RELU>
__device__ __forceinline__ void mlp_layer(const char* __restrict__ wf,
                                          const float* __restrict__ bias,
                                          int obase,
                                          const char* __restrict__ bufB,
                                          char* __restrict__ bufX, int lane) {
  f32x4 acc[2][4];
  f32x4 zero = {0.f, 0.f, 0.f, 0.f};
#pragma unroll
  for (int i = 0; i < 2; ++i)
#pragma unroll
    for (int j = 0; j < 4; ++j) acc[i][j] = zero;

#pragma unroll
  for (int kt = 0; kt < 8; ++kt) {
    bf16x8 bfr[4], afr[2];
#pragma unroll
    for (int bt = 0; bt < 4; ++bt)
      bfr[bt] = *(const bf16x8*)(bufB + (bt * 8 + kt) * 1024 + lane * 16);
#pragma unroll
    for (int ot = 0; ot < 2; ++ot)
      afr[ot] = *(const bf16x8*)(wf + (ot * 8 + kt) * 1024 + lane * 16);
#pragma unroll
    for (int ot = 0; ot < 2; ++ot)
#pragma unroll
      for (int bt = 0; bt < 4; ++bt) acc[ot][bt] = mfma16(afr[ot], bfr[bt], acc[ot][bt]);
  }

  int g = lane >> 4, lm = lane & 15;
#pragma unroll
  for (int ot = 0; ot < 2; ++ot) {
    f32x4 bv = *(const f32x4*)(bias + ot * 16 + 4 * g);
    int i0 = obase + ot * 16 + 4 * g;          // output index of reg r=0
    int ktp = i0 >> 5;
    int lanep = ((i0 & 31) >> 3) * 16 + lm;
    int byo = (i0 & 7) * 2;                    // 0 or 8
#pragma unroll
    for (int bt = 0; bt < 4; ++bt) {
      float v0 = acc[ot][bt].x + bv.x;
      float v1 = acc[ot][bt].y + bv.y;
      float v2 = acc[ot][bt].z + bv.z;
      float v3 = acc[ot][bt].w + bv.w;
      if (RELU) {
        v0 = fmaxf(v0, 0.f); v1 = fmaxf(v1, 0.f);
        v2 = fmaxf(v2, 0.f); v3 = fmaxf(v3, 0.f);
      }
      u16x4 pk = {f2bf(v0), f2bf(v1), f2bf(v2), f2bf(v3)};
      *(u16x4*)(bufX + (bt * 8 + ktp) * 1024 + lanep * 16 + byo) = pk;
    }
  }
}

__global__ __launch_bounds__(512, 4) void mlp_fused(
    const unsigned short* __restrict__ stateb, const char* __restrict__ W0f,
    const char* __restrict__ W1f, const char* __restrict__ W2f,
    const float* __restrict__ bias0, const float* __restrict__ bias1,
    const float* __restrict__ bias2, float* __restrict__ y2) {
  __shared__ char lds[65536];
  char* bufA = lds;            // state frags, later x2 frags
  char* bufX = lds + 32768;    // x1 frags
  int tid = threadIdx.x, w = tid >> 6, lane = tid & 63;
  int es = blockIdx.y, b0 = blockIdx.x * 64;

  // stage state tile [64 rows][256] as 32 B-frags (1 KB each)
#pragma unroll
  for (int it = 0; it < 4; ++it) {
    int F = it * 8 + w, bt = F >> 3, kt = F & 7;
    const unsigned short* src =
        stateb + (size_t)(b0 + bt * 16 + (lane & 15)) * 256 + kt * 32 + (lane >> 4) * 8;
    u16x8 v = *(const u16x8*)src;
    *(u16x8*)(bufA + F * 1024 + lane * 16) = v;
  }
  __syncthreads();

  mlp_layer<1>(W0f + (size_t)(es * 16 + w * 2) * 8192, bias0 + es * 256 + w * 32,
               w * 32, bufA, bufX, lane);
  __syncthreads();
  mlp_layer<1>(W1f + (size_t)(es * 16 + w * 2) * 8192, bias1 + es * 256 + w * 32,
               w * 32, bufX, bufA, lane);
  __syncthreads();

  // layer 2: O padded to 32; wave w handles (osub = w>>2, bt = w&3)
  int osub = w >> 2, bt2 = w & 3;
  f32x4 acc2 = {0.f, 0.f, 0.f, 0.f};
  const char* w2 = W2f + (size_t)es * 16384 + osub * 8192;
#pragma unroll
  for (int kt = 0; kt < 8; ++kt) {
    bf16x8 b = *(const bf16x8*)(bufA + (bt2 * 8 + kt) * 1024 + lane * 16);
    bf16x8 a = *(const bf16x8*)(w2 + kt * 1024 + lane * 16);
    acc2 = mfma16(a, b, acc2);
  }
  int g = lane >> 4, lm = lane & 15;
  int b_idx = b0 + bt2 * 16 + lm;
  f32x4 bv = *(const f32x4*)(bias2 + es * 32 + osub * 16 + 4 * g);
#pragma unroll
  for (int r = 0; r < 4; ++r) {
    int o = osub * 16 + 4 * g + r;
    float v = (r == 0 ? acc2.x : r == 1 ? acc2.y : r == 2 ? acc2.z : acc2.w);
    float bb = (r == 0 ? bv.x : r == 1 ? bv.y : r == 2 ? bv.z : bv.w);
    if (o < 18) y2[(size_t)(es * 18 + o) * 4096 + b_idx] = v + bb;
  }
}

// ---------------- ensemble mean / variance + KL final ------------------------
__global__ __launch_bounds__(256) void stats_kernel(const float* __restrict__ y2,
                                                    const float* __restrict__ partials,
                                                    float* __restrict__ out) {
  if (blockIdx.x == 0 && threadIdx.x < 64) {
    float acc = 0.f;
    for (int i = threadIdx.x; i < 512; i += 64) acc += partials[i];
#pragma unroll
    for (int m = 32; m >= 1; m >>= 1) acc += __shfl_xor(acc, m);
    if (threadIdx.x == 0) out[446464] = acc * 0.2f;
  }
  int idx = blockIdx.x * 256 + threadIdx.x;  // a*4096 + b
  if (idx >= 18 * 4096) return;
  int a = idx >> 12, b = idx & 4095;
  float qs = 0.f, qq = 0.f;
#pragma unroll
  for (int e = 0; e < 5; ++e) {
    float v = 0.f;
#pragma unroll
    for (int s = 0; s < 10; ++s) v += y2[(size_t)((e * 10 + s) * 18 + a) * 4096 + b];
    v *= 0.1f;
    qs += v;
    qq += v * v;
  }
  float mean = qs * 0.2f;
  float var = fmaxf((qq - 5.f * mean * mean) * 0.25f, 0.f);
  out[b * 18 + a] = mean;
  out[73728 + b * 18 + a] = var;
}

// ------------------------------- heads ---------------------------------------
__global__ __launch_bounds__(256) void heads_kernel(
    const float* __restrict__ uh_w1, const float* __restrict__ uh_b1,
    const float* __restrict__ uh_w2, const float* __restrict__ uh_b2,
    const float* __restrict__ rh_w1, const float* __restrict__ rh_b1,
    const float* __restrict__ rh_w2, const float* __restrict__ rh_b2,
    float* __restrict__ out) {
  __shared__ float rin[54];
  __shared__ float h[256];
  int b = blockIdx.x, t = threadIdx.x;
  if (t < 36) rin[t] = (t < 18) ? out[b * 18 + t] : out[73728 + b * 18 + (t - 18)];
  __syncthreads();

  {
    float acc = uh_b1[t];
#pragma unroll
    for (int j = 0; j < 36; ++j) acc += rin[j] * uh_w1[t * 36 + j];
    h[t] = fmaxf(acc, 0.f);
  }
  __syncthreads();

  int w = t >> 6, lane = t & 63;
  for (int idx = 0; idx < 5; ++idx) {
    int a = idx * 4 + w;
    if (a < 18) {
      float p = 0.f;
#pragma unroll
      for (int j = 0; j < 4; ++j) p += h[lane + 64 * j] * uh_w2[a * 256 + lane + 64 * j];
#pragma unroll
      for (int m = 32; m >= 1; m >>= 1) p += __shfl_xor(p, m);
      if (lane == 0) {
        float alea = softplus_f(p + uh_b2[a]);
        float qm = rin[a], epi = rin[18 + a];
        float tu = epi + alea;
        float s2 = 2.f * sqrtf(tu);
        out[2 * 73728 + b * 18 + a] = alea;
        out[3 * 73728 + b * 18 + a] = tu;
        out[4 * 73728 + b * 18 + a] = qm - s2;
        out[5 * 73728 + b * 18 + a] = qm + s2;
        rin[36 + a] = alea;
      }
    }
  }
  __syncthreads();

  {
    float acc = rh_b1[t];
#pragma unroll
    for (int j = 0; j < 54; ++j) acc += rin[j] * rh_w1[t * 54 + j];
    h[t] = fmaxf(acc, 0.f);
  }
  __syncthreads();
  if (w == 0) {
    float p = 0.f;
#pragma unroll
    for (int j = 0; j < 4; ++j) p += h[lane + 64 * j] * rh_w2[lane + 64 * j];
#pragma unroll
    for (int m = 32; m >= 1; m >>= 1) p += __shfl_xor(p, m);
    if (lane == 0) out[6 * 73728 + b] = p + rh_b2[0];
  }
}

// ------------------------------ launch ---------------------------------------
extern "C" void kernel_launch(void* const* d_in, const int* in_sizes, int n_in,
                              void* d_out, int out_size, void* d_ws, size_t ws_size,
                              hipStream_t stream) {
  const float* state = (const float*)d_in[0];
  const float* w_mu0 = (const float*)d_in[2];
  const float* w_rho0 = (const float*)d_in[3];
  const float* b_mu0 = (const float*)d_in[4];
  const float* b_rho0 = (const float*)d_in[5];
  const float* w_eps0 = (const float*)d_in[6];
  const float* b_eps0 = (const float*)d_in[7];
  const float* w_mu1 = (const float*)d_in[8];
  const float* w_rho1 = (const float*)d_in[9];
  const float* b_mu1 = (const float*)d_in[10];
  const float* b_rho1 = (const float*)d_in[11];
  const float* w_eps1 = (const float*)d_in[12];
  const float* b_eps1 = (const float*)d_in[13];
  const float* w_mu2 = (const float*)d_in[14];
  const float* w_rho2 = (const float*)d_in[15];
  const float* b_mu2 = (const float*)d_in[16];
  const float* b_rho2 = (const float*)d_in[17];
  const float* w_eps2 = (const float*)d_in[18];
  const float* b_eps2 = (const float*)d_in[19];
  const float* uh_w1 = (const float*)d_in[20];
  const float* uh_b1 = (const float*)d_in[21];
  const float* uh_w2 = (const float*)d_in[22];
  const float* uh_b2 = (const float*)d_in[23];
  const float* rh_w1 = (const float*)d_in[24];
  const float* rh_b1 = (const float*)d_in[25];
  const float* rh_w2 = (const float*)d_in[26];
  const float* rh_b2 = (const float*)d_in[27];
  float* out = (float*)d_out;

  char* ws = (char*)d_ws;
  unsigned short* stateb = (unsigned short*)ws;          // 2 MB
  char* W0f = ws + 2097152;                              // 6.55 MB
  char* W1f = W0f + 6553600;
  char* W2f = W1f + 6553600;                             // 0.82 MB
  float* bias0 = (float*)(W2f + 819200);                 // 12800 f
  float* bias1 = bias0 + 12800;
  float* bias2 = bias1 + 12800;                          // 1600 f
  float* y2 = bias2 + 1600;                              // 50*18*4096 f
  float* klpart = y2 + (size_t)50 * 18 * 4096;           // 512 f

  prep_kernel<<<4531, 256, 0, stream>>>(
      state, stateb, w_mu0, w_rho0, w_eps0, W0f, w_mu1, w_rho1, w_eps1, W1f,
      w_mu2, w_rho2, w_eps2, W2f, b_mu0, b_rho0, b_eps0, b_mu1, b_rho1, b_eps1,
      b_mu2, b_rho2, b_eps2, bias0, bias1, bias2, klpart);
  mlp_fused<<<dim3(64, 50), 512, 0, stream>>>(stateb, W0f, W1f, W2f, bias0, bias1,
                                              bias2, y2);
  stats_kernel<<<288, 256, 0, stream>>>(y2, klpart, out);
  heads_kernel<<<4096, 256, 0, stream>>>(uh_w1, uh_b1, uh_w2, uh_b2, rh_w1, rh_b1,
                                         rh_w2, rh_b2, out);
}

// Round 3
// 138.047 us; speedup vs baseline: 1.4904x; 1.2339x over previous
//
#include <hip/hip_runtime.h>
#include <hip/hip_bf16.h>

// ---------------------------------------------------------------------------
// UncertaintyAwareQNetwork: E=5 ensemble x NS=10 MC samples, B=4096 rows.
// Pipeline (3 dispatches):
//   prep:   state->bf16, realized weights (MFMA-frag-major), biases, KL partials
//   mlp:    fused 3-layer MFMA kernel, 512 thr/block, XCD es-affinity swizzle
//   heads:  ensemble stats + uncertainty/risk heads + KL final
// ---------------------------------------------------------------------------

typedef __bf16 bf16x8 __attribute__((ext_vector_type(8)));
typedef float f32x4 __attribute__((ext_vector_type(4)));
typedef unsigned short u16x4 __attribute__((ext_vector_type(4)));
typedef unsigned short u16x8 __attribute__((ext_vector_type(8)));

__device__ __forceinline__ unsigned short f2bf(float f) {
  unsigned int u = __builtin_bit_cast(unsigned int, f);
  u += 0x7fffu + ((u >> 16) & 1u);
  return (unsigned short)(u >> 16);
}

__device__ __forceinline__ float softplus_f(float x) {
  return (x > 20.f) ? x : __logf(1.f + __expf(x));
}

__device__ __forceinline__ f32x4 mfma16(bf16x8 a, bf16x8 b, f32x4 c) {
  return __builtin_amdgcn_mfma_f32_16x16x32_bf16(a, b, c, 0, 0, 0);
}

// ------------------- prep bodies (fused into one kernel) --------------------

__device__ __forceinline__ void scvt_body(int gid, const float* __restrict__ s,
                                          unsigned short* __restrict__ d) {
  const f32x4* p = (const f32x4*)(s + (size_t)gid * 8);
  f32x4 x0 = p[0], x1 = p[1];
  u16x8 v = {f2bf(x0.x), f2bf(x0.y), f2bf(x0.z), f2bf(x0.w),
             f2bf(x1.x), f2bf(x1.y), f2bf(x1.z), f2bf(x1.w)};
  *(u16x8*)(d + (size_t)gid * 8) = v;
}

// frag id = (es*(OPAD/16) + osub)*8 + kt ; lane l holds
// W[o = osub*16 + l%16][i = kt*32 + (l/16)*8 + 0..7]
template <int O, int OPAD>
__device__ __forceinline__ void wgen_body(int gid, const float* __restrict__ wmu,
                                          const float* __restrict__ wrho,
                                          const float* __restrict__ weps,
                                          char* __restrict__ wf) {
  int es = gid / (OPAD * 32);
  int rem = gid - es * (OPAD * 32);
  int o = rem >> 5;
  int i8 = (rem & 31) * 8;
  int e = es / 10, s = es - e * 10;
  float v[8];
  if (O == OPAD || o < O) {
    const float* mu = wmu + ((size_t)(e * O + o)) * 256 + i8;
    const float* rho = wrho + ((size_t)(e * O + o)) * 256 + i8;
    const float* eps = weps + ((size_t)((e * 10 + s) * O + o)) * 256 + i8;
#pragma unroll
    for (int j = 0; j < 8; ++j) v[j] = mu[j] + softplus_f(rho[j]) * eps[j];
  } else {
#pragma unroll
    for (int j = 0; j < 8; ++j) v[j] = 0.f;
  }
  u16x8 pk = {f2bf(v[0]), f2bf(v[1]), f2bf(v[2]), f2bf(v[3]),
              f2bf(v[4]), f2bf(v[5]), f2bf(v[6]), f2bf(v[7])};
  int osub = o >> 4, om = o & 15, kt = i8 >> 5, jj = (i8 >> 3) & 3;
  int lane = jj * 16 + om;
  *(u16x8*)(wf + (size_t)(((es * (OPAD / 16) + osub) * 8 + kt) * 64 + lane) * 16) = pk;
}

__global__ __launch_bounds__(256) void prep_kernel(
    const float* __restrict__ state, unsigned short* __restrict__ stateb,
    const float* __restrict__ wmu0, const float* __restrict__ wrho0,
    const float* __restrict__ weps0, char* __restrict__ W0f,
    const float* __restrict__ wmu1, const float* __restrict__ wrho1,
    const float* __restrict__ weps1, char* __restrict__ W1f,
    const float* __restrict__ wmu2, const float* __restrict__ wrho2,
    const float* __restrict__ weps2, char* __restrict__ W2f,
    const float* __restrict__ bmu0, const float* __restrict__ brho0,
    const float* __restrict__ beps0, const float* __restrict__ bmu1,
    const float* __restrict__ brho1, const float* __restrict__ beps1,
    const float* __restrict__ bmu2, const float* __restrict__ brho2,
    const float* __restrict__ beps2, float* __restrict__ bias0,
    float* __restrict__ bias1, float* __restrict__ bias2,
    float* __restrict__ partials) {
  int bid = blockIdx.x, t = threadIdx.x;
  if (bid < 512) {
    scvt_body(bid * 256 + t, state, stateb);
  } else if (bid < 2112) {
    wgen_body<256, 256>((bid - 512) * 256 + t, wmu0, wrho0, weps0, W0f);
  } else if (bid < 3712) {
    wgen_body<256, 256>((bid - 2112) * 256 + t, wmu1, wrho1, weps1, W1f);
  } else if (bid < 3912) {
    wgen_body<18, 32>((bid - 3712) * 256 + t, wmu2, wrho2, weps2, W2f);
  } else if (bid < 4019) {
    int gid = (bid - 3912) * 256 + t;
    if (gid < 12800) {
      int es = gid >> 8, o = gid & 255, e = es / 10, s = es - e * 10;
      bias0[gid] = bmu0[e * 256 + o] + softplus_f(brho0[e * 256 + o]) * beps0[(e * 10 + s) * 256 + o];
    } else if (gid < 25600) {
      int id = gid - 12800;
      int es = id >> 8, o = id & 255, e = es / 10, s = es - e * 10;
      bias1[id] = bmu1[e * 256 + o] + softplus_f(brho1[e * 256 + o]) * beps1[(e * 10 + s) * 256 + o];
    } else if (gid < 27200) {
      int id = gid - 25600;
      int es = id >> 5, o = id & 31, e = es / 10, s = es - e * 10;
      bias2[id] = (o < 18)
          ? bmu2[e * 18 + o] + softplus_f(brho2[e * 18 + o]) * beps2[(e * 10 + s) * 18 + o]
          : 0.f;
    }
  } else {
    int lb = bid - 4019;  // 0..511
    float acc = 0.f;
    for (int i = lb * 256 + t; i < 681050; i += 512 * 256) {
      const float *mu, *rho;
      int j = i;
      if (j < 327680) { mu = wmu0; rho = wrho0; }
      else if ((j -= 327680) < 327680) { mu = wmu1; rho = wrho1; }
      else if ((j -= 327680) < 23040) { mu = wmu2; rho = wrho2; }
      else if ((j -= 23040) < 1280) { mu = bmu0; rho = brho0; }
      else if ((j -= 1280) < 1280) { mu = bmu1; rho = brho1; }
      else { j -= 1280; mu = bmu2; rho = brho2; }
      float m = mu[j];
      float sg = softplus_f(rho[j]);
      acc += -__logf(sg) + (sg * sg + m * m) * 0.5f - 0.5f;
    }
#pragma unroll
    for (int m = 32; m >= 1; m >>= 1) acc += __shfl_xor(acc, m);
    __shared__ float wsum[4];
    if ((t & 63) == 0) wsum[t >> 6] = acc;
    __syncthreads();
    if (t == 0) partials[lb] = wsum[0] + wsum[1] + wsum[2] + wsum[3];
  }
}

// ------------------------------ fused MLP ------------------------------------
// Transposed formulation: D[o][b] = sum_i W[o][i] * x[b][i].
// 8 waves/block; wave w owns o-subtiles {2w, 2w+1}. 2-deep frag double-buffer
// + setprio around the MFMA cluster.
template <int RELU>
__device__ __forceinline__ void mlp_layer(const char* __restrict__ wf,
                                          const float* __restrict__ bias,
                                          int obase,
                                          const char* __restrict__ bufB,
                                          char* __restrict__ bufX, int lane) {
  f32x4 acc[2][4];
  f32x4 zero = {0.f, 0.f, 0.f, 0.f};
#pragma unroll
  for (int i = 0; i < 2; ++i)
#pragma unroll
    for (int j = 0; j < 4; ++j) acc[i][j] = zero;

  bf16x8 bfr[2][4], afr[2][2];
#pragma unroll
  for (int bt = 0; bt < 4; ++bt)
    bfr[0][bt] = *(const bf16x8*)(bufB + (bt * 8) * 1024 + lane * 16);
#pragma unroll
  for (int ot = 0; ot < 2; ++ot)
    afr[0][ot] = *(const bf16x8*)(wf + (ot * 8) * 1024 + lane * 16);

#pragma unroll
  for (int kt = 0; kt < 8; ++kt) {
    const int cur = kt & 1, nxt = cur ^ 1;
    if (kt < 7) {
#pragma unroll
      for (int bt = 0; bt < 4; ++bt)
        bfr[nxt][bt] = *(const bf16x8*)(bufB + (bt * 8 + kt + 1) * 1024 + lane * 16);
#pragma unroll
      for (int ot = 0; ot < 2; ++ot)
        afr[nxt][ot] = *(const bf16x8*)(wf + (ot * 8 + kt + 1) * 1024 + lane * 16);
    }
    __builtin_amdgcn_s_setprio(1);
#pragma unroll
    for (int ot = 0; ot < 2; ++ot)
#pragma unroll
      for (int bt = 0; bt < 4; ++bt)
        acc[ot][bt] = mfma16(afr[cur][ot], bfr[cur][bt], acc[ot][bt]);
    __builtin_amdgcn_s_setprio(0);
  }

  int g = lane >> 4, lm = lane & 15;
#pragma unroll
  for (int ot = 0; ot < 2; ++ot) {
    f32x4 bv = *(const f32x4*)(bias + ot * 16 + 4 * g);
    int i0 = obase + ot * 16 + 4 * g;          // output index of reg r=0
    int ktp = i0 >> 5;
    int lanep = ((i0 & 31) >> 3) * 16 + lm;
    int byo = (i0 & 7) * 2;                    // 0 or 8
#pragma unroll
    for (int bt = 0; bt < 4; ++bt) {
      float v0 = acc[ot][bt].x + bv.x;
      float v1 = acc[ot][bt].y + bv.y;
      float v2 = acc[ot][bt].z + bv.z;
      float v3 = acc[ot][bt].w + bv.w;
      if (RELU) {
        v0 = fmaxf(v0, 0.f); v1 = fmaxf(v1, 0.f);
        v2 = fmaxf(v2, 0.f); v3 = fmaxf(v3, 0.f);
      }
      u16x4 pk = {f2bf(v0), f2bf(v1), f2bf(v2), f2bf(v3)};
      *(u16x4*)(bufX + (bt * 8 + ktp) * 1024 + lanep * 16 + byo) = pk;
    }
  }
}

__global__ __launch_bounds__(512, 4) void mlp_fused(
    const unsigned short* __restrict__ stateb, const char* __restrict__ W0f,
    const char* __restrict__ W1f, const char* __restrict__ W2f,
    const float* __restrict__ bias0, const float* __restrict__ bias1,
    const float* __restrict__ bias2, float* __restrict__ y2) {
  __shared__ char lds[65536];
  char* bufA = lds;            // state frags, later x2 frags
  char* bufX = lds + 32768;    // x1 frags
  int tid = threadIdx.x, w = tid >> 6, lane = tid & 63;

  // XCD-chunked bijective swizzle: 3200 = 8 XCD * 400; same-es blocks share L2.
  int bid = blockIdx.x;
  int lin = (bid & 7) * 400 + (bid >> 3);
  int es = lin >> 6, b0 = (lin & 63) * 64;

  // stage state tile [64 rows][256] as 32 B-frags (1 KB each)
#pragma unroll
  for (int it = 0; it < 4; ++it) {
    int F = it * 8 + w, bt = F >> 3, kt = F & 7;
    const unsigned short* src =
        stateb + (size_t)(b0 + bt * 16 + (lane & 15)) * 256 + kt * 32 + (lane >> 4) * 8;
    u16x8 v = *(const u16x8*)src;
    *(u16x8*)(bufA + F * 1024 + lane * 16) = v;
  }
  __syncthreads();

  mlp_layer<1>(W0f + (size_t)(es * 16 + w * 2) * 8192, bias0 + es * 256 + w * 32,
               w * 32, bufA, bufX, lane);
  __syncthreads();
  mlp_layer<1>(W1f + (size_t)(es * 16 + w * 2) * 8192, bias1 + es * 256 + w * 32,
               w * 32, bufX, bufA, lane);
  __syncthreads();

  // layer 2: O padded to 32; wave w handles (osub = w>>2, bt = w&3)
  int osub = w >> 2, bt2 = w & 3;
  f32x4 acc2 = {0.f, 0.f, 0.f, 0.f};
  const char* w2 = W2f + (size_t)es * 16384 + osub * 8192;
#pragma unroll
  for (int kt = 0; kt < 8; ++kt) {
    bf16x8 b = *(const bf16x8*)(bufA + (bt2 * 8 + kt) * 1024 + lane * 16);
    bf16x8 a = *(const bf16x8*)(w2 + kt * 1024 + lane * 16);
    acc2 = mfma16(a, b, acc2);
  }
  int g = lane >> 4, lm = lane & 15;
  int b_idx = b0 + bt2 * 16 + lm;
  f32x4 bv = *(const f32x4*)(bias2 + es * 32 + osub * 16 + 4 * g);
#pragma unroll
  for (int r = 0; r < 4; ++r) {
    int o = osub * 16 + 4 * g + r;
    float v = (r == 0 ? acc2.x : r == 1 ? acc2.y : r == 2 ? acc2.z : acc2.w);
    float bb = (r == 0 ? bv.x : r == 1 ? bv.y : r == 2 ? bv.z : bv.w);
    if (o < 18) y2[(size_t)(es * 18 + o) * 4096 + b_idx] = v + bb;
  }
}

// ------------- heads (with fused ensemble stats + KL final) ------------------
__global__ __launch_bounds__(256) void heads_kernel(
    const float* __restrict__ y2, const float* __restrict__ partials,
    const float* __restrict__ uh_w1, const float* __restrict__ uh_b1,
    const float* __restrict__ uh_w2, const float* __restrict__ uh_b2,
    const float* __restrict__ rh_w1, const float* __restrict__ rh_b1,
    const float* __restrict__ rh_w2, const float* __restrict__ rh_b2,
    float* __restrict__ out) {
  int b = blockIdx.x, t = threadIdx.x;
  if (b == 4096) {  // KL final reduce
    if (t < 64) {
      float acc = 0.f;
      for (int i = t; i < 512; i += 64) acc += partials[i];
#pragma unroll
      for (int m = 32; m >= 1; m >>= 1) acc += __shfl_xor(acc, m);
      if (t == 0) out[446464] = acc * 0.2f;
    }
    return;
  }

  __shared__ float qsE[90];
  __shared__ float rin[54];
  __shared__ float h[256];

  // per-(a,e) MC mean over s
  if (t < 90) {
    int a = t / 5, e = t - a * 5;
    float v = 0.f;
    const float* p = y2 + (size_t)(e * 10 * 18 + a) * 4096 + b;
#pragma unroll
    for (int s = 0; s < 10; ++s) v += p[(size_t)s * 18 * 4096];
    qsE[t] = v * 0.1f;
  }
  __syncthreads();
  if (t < 18) {
    float qs = 0.f, qq = 0.f;
#pragma unroll
    for (int e = 0; e < 5; ++e) {
      float v = qsE[t * 5 + e];
      qs += v;
      qq += v * v;
    }
    float mean = qs * 0.2f;
    float var = fmaxf((qq - 5.f * mean * mean) * 0.25f, 0.f);
    rin[t] = mean;
    rin[18 + t] = var;
    out[b * 18 + t] = mean;
    out[73728 + b * 18 + t] = var;
  }
  __syncthreads();

  // uncertainty hidden layer
  {
    float acc = uh_b1[t];
    const f32x4* wr = (const f32x4*)(uh_w1 + t * 36);
#pragma unroll
    for (int j = 0; j < 9; ++j) {
      f32x4 wv = wr[j];
      acc += wv.x * rin[j * 4] + wv.y * rin[j * 4 + 1] + wv.z * rin[j * 4 + 2] +
             wv.w * rin[j * 4 + 3];
    }
    h[t] = fmaxf(acc, 0.f);
  }
  __syncthreads();

  int w = t >> 6, lane = t & 63;
  for (int idx = 0; idx < 5; ++idx) {
    int a = idx * 4 + w;
    if (a < 18) {
      float p = 0.f;
#pragma unroll
      for (int j = 0; j < 4; ++j) p += h[lane + 64 * j] * uh_w2[a * 256 + lane + 64 * j];
#pragma unroll
      for (int m = 32; m >= 1; m >>= 1) p += __shfl_xor(p, m);
      if (lane == 0) {
        float alea = softplus_f(p + uh_b2[a]);
        float qm = rin[a], epi = rin[18 + a];
        float tu = epi + alea;
        float s2 = 2.f * sqrtf(tu);
        out[2 * 73728 + b * 18 + a] = alea;
        out[3 * 73728 + b * 18 + a] = tu;
        out[4 * 73728 + b * 18 + a] = qm - s2;
        out[5 * 73728 + b * 18 + a] = qm + s2;
        rin[36 + a] = alea;
      }
    }
  }
  __syncthreads();

  // risk hidden layer
  {
    float acc = rh_b1[t];
    const float2* wr2 = (const float2*)(rh_w1 + t * 54);
#pragma unroll
    for (int j = 0; j < 27; ++j) {
      float2 wv = wr2[j];
      acc += wv.x * rin[j * 2] + wv.y * rin[j * 2 + 1];
    }
    h[t] = fmaxf(acc, 0.f);
  }
  __syncthreads();
  if (w == 0) {
    float p = 0.f;
#pragma unroll
    for (int j = 0; j < 4; ++j) p += h[lane + 64 * j] * rh_w2[lane + 64 * j];
#pragma unroll
    for (int m = 32; m >= 1; m >>= 1) p += __shfl_xor(p, m);
    if (lane == 0) out[6 * 73728 + b] = p + rh_b2[0];
  }
}

// ------------------------------ launch ---------------------------------------
extern "C" void kernel_launch(void* const* d_in, const int* in_sizes, int n_in,
                              void* d_out, int out_size, void* d_ws, size_t ws_size,
                              hipStream_t stream) {
  const float* state = (const float*)d_in[0];
  const float* w_mu0 = (const float*)d_in[2];
  const float* w_rho0 = (const float*)d_in[3];
  const float* b_mu0 = (const float*)d_in[4];
  const float* b_rho0 = (const float*)d_in[5];
  const float* w_eps0 = (const float*)d_in[6];
  const float* b_eps0 = (const float*)d_in[7];
  const float* w_mu1 = (const float*)d_in[8];
  const float* w_rho1 = (const float*)d_in[9];
  const float* b_mu1 = (const float*)d_in[10];
  const float* b_rho1 = (const float*)d_in[11];
  const float* w_eps1 = (const float*)d_in[12];
  const float* b_eps1 = (const float*)d_in[13];
  const float* w_mu2 = (const float*)d_in[14];
  const float* w_rho2 = (const float*)d_in[15];
  const float* b_mu2 = (const float*)d_in[16];
  const float* b_rho2 = (const float*)d_in[17];
  const float* w_eps2 = (const float*)d_in[18];
  const float* b_eps2 = (const float*)d_in[19];
  const float* uh_w1 = (const float*)d_in[20];
  const float* uh_b1 = (const float*)d_in[21];
  const float* uh_w2 = (const float*)d_in[22];
  const float* uh_b2 = (const float*)d_in[23];
  const float* rh_w1 = (const float*)d_in[24];
  const float* rh_b1 = (const float*)d_in[25];
  const float* rh_w2 = (const float*)d_in[26];
  const float* rh_b2 = (const float*)d_in[27];
  float* out = (float*)d_out;

  char* ws = (char*)d_ws;
  unsigned short* stateb = (unsigned short*)ws;          // 2 MB
  char* W0f = ws + 2097152;                              // 6.55 MB
  char* W1f = W0f + 6553600;
  char* W2f = W1f + 6553600;                             // 0.82 MB
  float* bias0 = (float*)(W2f + 819200);                 // 12800 f
  float* bias1 = bias0 + 12800;
  float* bias2 = bias1 + 12800;                          // 1600 f
  float* y2 = bias2 + 1600;                              // 50*18*4096 f
  float* klpart = y2 + (size_t)50 * 18 * 4096;           // 512 f

  prep_kernel<<<4531, 256, 0, stream>>>(
      state, stateb, w_mu0, w_rho0, w_eps0, W0f, w_mu1, w_rho1, w_eps1, W1f,
      w_mu2, w_rho2, w_eps2, W2f, b_mu0, b_rho0, b_eps0, b_mu1, b_rho1, b_eps1,
      b_mu2, b_rho2, b_eps2, bias0, bias1, bias2, klpart);
  mlp_fused<<<3200, 512, 0, stream>>>(stateb, W0f, W1f, W2f, bias0, bias1,
                                      bias2, y2);
  heads_kernel<<<4097, 256, 0, stream>>>(y2, klpart, uh_w1, uh_b1, uh_w2, uh_b2,
                                         rh_w1, rh_b1, rh_w2, rh_b2, out);
}